// Round 20
// baseline (64.140 us; speedup 1.0000x reference)
//
#include <hip/hip_runtime.h>
#include <hip/hip_bf16.h>

#define D 256
#define NROWS 8192
#define LXV 4176         // Ut col stride per batch: 64 prefix + 4096 + 16 tail pad
#define VPAD 64
#define KXFB 1064960     // Kxf batch stride (u16): 260 tiles * 8 ks * 512

#define QBLK 16          // attn rows per block
#define SSTR 84          // Sb row stride (f32)
#define PSTR 104         // Pb row stride (u16), cols 80..95 zeroed
#define BSTR 264         // Bs row stride (u16)

typedef unsigned int u32;
typedef unsigned short u16;

typedef short bf16x8 __attribute__((ext_vector_type(8)));
typedef float f32x4 __attribute__((ext_vector_type(4)));

__device__ __forceinline__ u16 f2bf(float f) {
    u32 x = __float_as_uint(f);
    x += 0x7fffu + ((x >> 16) & 1u);
    return (u16)(x >> 16);
}
__device__ __forceinline__ u32 pk2(float a, float b) {
    return (u32)f2bf(a) | ((u32)f2bf(b) << 16);
}

// ---------------- Kernel 1: QKU projection ----------------
// grid (32, 12): blockIdx.x = row-group (fast dim -> XCD-shared H), blockIdx.y = slab.
// bx 0..3 = Q, 4..7 = K (R17-verified path, fragment-layout outputs).
// bx 8..11 = U: block computes its own Wvo slab (Wv @ Wo[:,slab]) redundantly via the
// same GEMM skeleton, parks packed bf16 in global WvoS (self-read only; identical
// cross-block writes benign), restages as B, then U = H @ Wvo + bvo -> Ut transposed.
__global__ __launch_bounds__(256) void qkv_mfma(
    const float* __restrict__ H,
    const float* __restrict__ Wq, const float* __restrict__ Wk,
    const float* __restrict__ Wv, const float* __restrict__ Wo,
    const float* __restrict__ bq, const float* __restrict__ bkb,
    const float* __restrict__ bvb,
    u16* __restrict__ Qf, u16* __restrict__ Kxf, u16* __restrict__ Ut,
    u16* __restrict__ WvoS)
{
    __shared__ u16 As[64 * 256];        // 32768 B
    __shared__ u16 Bs[64 * BSTR];       // 33792 B
    __shared__ u16 Eb[64 * 72];         // 9216 B

    const int tid = threadIdx.x;
    const int by = blockIdx.x;          // 0..31 row group
    const int bx = blockIdx.y;          // 0..11 slab
    const int mat = bx >> 2;            // 0=Q 1=K 2=U
    const int n0 = (bx & 3) * 64;
    const int row0 = by * 256;
    const int batch = by >> 4;
    const int lrow0 = row0 & 4095;

    const int lane = tid & 63, w = tid >> 6;
    const int l15 = lane & 15, lhi = lane >> 4;
    const int rt2 = (w & 1) * 2, ct2 = (w >> 1) * 2;

    if (mat == 2) {
        // ================= U path =================
        const int sl = bx & 3;
        float* red = (float*)Eb;        // 256 f32 partials for bvo

        // bvo partials: red[p*64+j] = sum_{m in p-chunk} bv[m]*Wo[m][n0+j]
        {
            const int j = tid & 63, p = tid >> 6;
            float part = 0.f;
            for (int m = p * 64; m < p * 64 + 64; ++m)
                part += bvb[m] * Wo[(size_t)m * 256 + n0 + j];
            red[p * 64 + j] = part;
        }
        // stage B = Wo slab (packed [n][k])
        {
            const int kp = tid & 31, ng = tid >> 5;
            u32* bd = (u32*)Bs;
            #pragma unroll
            for (int s = 0; s < 4; ++s) {
                const float* wr = Wo + (size_t)(s * 64 + 2 * kp) * 256 + n0 + ng * 8;
                float4 a0 = *(const float4*)(wr);
                float4 a1 = *(const float4*)(wr + 4);
                float4 b0 = *(const float4*)(wr + 256);
                float4 b1 = *(const float4*)(wr + 260);
                bd[(ng * 8 + 0) * 132 + s * 32 + kp] = pk2(a0.x, b0.x);
                bd[(ng * 8 + 1) * 132 + s * 32 + kp] = pk2(a0.y, b0.y);
                bd[(ng * 8 + 2) * 132 + s * 32 + kp] = pk2(a0.z, b0.z);
                bd[(ng * 8 + 3) * 132 + s * 32 + kp] = pk2(a0.w, b0.w);
                bd[(ng * 8 + 4) * 132 + s * 32 + kp] = pk2(a1.x, b1.x);
                bd[(ng * 8 + 5) * 132 + s * 32 + kp] = pk2(a1.y, b1.y);
                bd[(ng * 8 + 6) * 132 + s * 32 + kp] = pk2(a1.z, b1.z);
                bd[(ng * 8 + 7) * 132 + s * 32 + kp] = pk2(a1.w, b1.w);
            }
        }
        // stage A = Wv tile 0
        {
            const int r = tid >> 2, cb = (tid & 3) * 64;
            const float* hp = Wv + (size_t)r * 256 + cb;
            const int swz = (r & 7) << 3;
            #pragma unroll
            for (int i = 0; i < 16; ++i) {
                float4 h4 = *(const float4*)(hp + i * 4);
                uint2 pv; pv.x = pk2(h4.x, h4.y); pv.y = pk2(h4.z, h4.w);
                *(uint2*)(As + ((r * 256 + cb + i * 4) ^ swz)) = pv;
            }
        }
        __syncthreads();   // S1: red + Bs + As ready

        // bvo for this thread's 2 output cols (consumed in U epilogue)
        float bvo_r[2];
        #pragma unroll
        for (int cc = 0; cc < 2; ++cc) {
            const int dl = (ct2 + cc) * 16 + l15;
            bvo_r[cc] = red[dl] + red[64 + dl] + red[128 + dl] + red[192 + dl];
        }
        // Ut virtual prefix for this slab (designated blocks, 64 dims x 64 cols)
        if ((by & 15) == 0) {
            const int batch2 = by >> 4;
            const int dm = tid >> 2, c0 = (tid & 3) * 16;
            const float bsum = red[dm] + red[64 + dm] + red[128 + dm] + red[192 + dm];
            const u16 val = f2bf(bsum);
            const u32 vv = (u32)val | ((u32)val << 16);
            uint4 o; o.x = vv; o.y = vv; o.z = vv; o.w = vv;
            u16* dst = Ut + ((size_t)batch2 * 256 + n0 + dm) * LXV + c0;
            *(uint4*)dst = o;
            *(uint4*)(dst + 8) = o;
        }

        // ---- GEMM 1: Wvo slab = Wv @ Wo_slab -> WvoS (packed bf16 [n][k]) ----
        u32* wdst = (u32*)(WvoS + (size_t)sl * 16384);
        for (int t = 0; t < 4; ++t) {
            f32x4 acc[2][2];
            #pragma unroll
            for (int rr = 0; rr < 2; ++rr)
                #pragma unroll
                for (int cc = 0; cc < 2; ++cc)
                    acc[rr][cc] = (f32x4){0.f, 0.f, 0.f, 0.f};
            #pragma unroll
            for (int rr = 0; rr < 2; ++rr) {
                const int rowa = (rt2 + rr) * 16 + l15;
                const int swa = (rowa & 7) << 3;
                bf16x8 af[8];
                #pragma unroll
                for (int ks = 0; ks < 8; ++ks)
                    af[ks] = *(const bf16x8*)(As + ((rowa * 256 + ks * 32 + lhi * 8) ^ swa));
                #pragma unroll
                for (int ks = 0; ks < 8; ++ks)
                    #pragma unroll
                    for (int cc = 0; cc < 2; ++cc) {
                        bf16x8 bf = *(const bf16x8*)&Bs[((ct2 + cc) * 16 + l15) * BSTR + ks * 32 + lhi * 8];
                        acc[rr][cc] = __builtin_amdgcn_mfma_f32_16x16x32_bf16(af[ks], bf, acc[rr][cc], 0, 0, 0);
                    }
            }
            __syncthreads();   // MFMA done reading As
            if (t < 3) {
                const int r = tid >> 2, cb = (tid & 3) * 64;
                const float* hp = Wv + (size_t)((t + 1) * 64 + r) * 256 + cb;
                const int swz = (r & 7) << 3;
                #pragma unroll
                for (int i = 0; i < 16; ++i) {
                    float4 h4 = *(const float4*)(hp + i * 4);
                    uint2 pv; pv.x = pk2(h4.x, h4.y); pv.y = pk2(h4.z, h4.w);
                    *(uint2*)(As + ((r * 256 + cb + i * 4) ^ swz)) = pv;
                }
            }
            // park Wvo tile t: rows k = t*64 + rowlocal, cols n
            #pragma unroll
            for (int cc = 0; cc < 2; ++cc) {
                const int n = (ct2 + cc) * 16 + l15;
                #pragma unroll
                for (int rr = 0; rr < 2; ++rr) {
                    const int k2 = t * 32 + (rt2 + rr) * 8 + lhi * 2;
                    uint2 pv;
                    pv.x = pk2(acc[rr][cc][0], acc[rr][cc][1]);
                    pv.y = pk2(acc[rr][cc][2], acc[rr][cc][3]);
                    *(uint2*)&wdst[n * 128 + k2] = pv;
                }
            }
            __syncthreads();   // As(t+1) ready; vmem drained (incl. WvoS stores)
        }

        // ---- restage B = WvoS slab (own writes, L2-visible after barrier drain) ----
        {
            const u16* wsrc = WvoS + (size_t)sl * 16384;
            #pragma unroll
            for (int i = 0; i < 8; ++i) {
                const int u = i * 256 + tid;
                const int col = u >> 5, seg = u & 31;
                uint4 v = *(const uint4*)&wsrc[col * 256 + seg * 8];
                *(uint4*)&Bs[col * BSTR + seg * 8] = v;
            }
        }
        // stage A = H tile 0
        {
            const int r = tid >> 2, cb = (tid & 3) * 64;
            const float* hp = H + (size_t)(row0 + r) * 256 + cb;
            const int swz = (r & 7) << 3;
            #pragma unroll
            for (int i = 0; i < 16; ++i) {
                float4 h4 = *(const float4*)(hp + i * 4);
                uint2 pv; pv.x = pk2(h4.x, h4.y); pv.y = pk2(h4.z, h4.w);
                *(uint2*)(As + ((r * 256 + cb + i * 4) ^ swz)) = pv;
            }
        }
        __syncthreads();

        // ---- GEMM 2: U tile-loop = H @ Wvo + bvo -> Ut (transposed store) ----
        for (int t = 0; t < 4; ++t) {
            f32x4 acc[2][2];
            #pragma unroll
            for (int rr = 0; rr < 2; ++rr)
                #pragma unroll
                for (int cc = 0; cc < 2; ++cc)
                    acc[rr][cc] = (f32x4){0.f, 0.f, 0.f, 0.f};
            #pragma unroll
            for (int rr = 0; rr < 2; ++rr) {
                const int rowa = (rt2 + rr) * 16 + l15;
                const int swa = (rowa & 7) << 3;
                bf16x8 af[8];
                #pragma unroll
                for (int ks = 0; ks < 8; ++ks)
                    af[ks] = *(const bf16x8*)(As + ((rowa * 256 + ks * 32 + lhi * 8) ^ swa));
                #pragma unroll
                for (int ks = 0; ks < 8; ++ks)
                    #pragma unroll
                    for (int cc = 0; cc < 2; ++cc) {
                        bf16x8 bf = *(const bf16x8*)&Bs[((ct2 + cc) * 16 + l15) * BSTR + ks * 32 + lhi * 8];
                        acc[rr][cc] = __builtin_amdgcn_mfma_f32_16x16x32_bf16(af[ks], bf, acc[rr][cc], 0, 0, 0);
                    }
            }
            __syncthreads();
            #pragma unroll
            for (int cc = 0; cc < 2; ++cc) {
                const int dl = (ct2 + cc) * 16 + l15;
                #pragma unroll
                for (int rr = 0; rr < 2; ++rr)
                    #pragma unroll
                    for (int reg = 0; reg < 4; ++reg)
                        Eb[dl * 72 + (rt2 + rr) * 16 + lhi * 4 + reg] = f2bf(acc[rr][cc][reg] + bvo_r[cc]);
            }
            if (t < 3) {
                const int r = tid >> 2, cb = (tid & 3) * 64;
                const float* hp = H + (size_t)(row0 + (t + 1) * 64 + r) * 256 + cb;
                const int swz = (r & 7) << 3;
                #pragma unroll
                for (int i = 0; i < 16; ++i) {
                    float4 h4 = *(const float4*)(hp + i * 4);
                    uint2 pv; pv.x = pk2(h4.x, h4.y); pv.y = pk2(h4.z, h4.w);
                    *(uint2*)(As + ((r * 256 + cb + i * 4) ^ swz)) = pv;
                }
            }
            __syncthreads();
            {
                const int d2 = tid >> 2, q = tid & 3;
                uint4 v0 = *(const uint4*)&Eb[d2 * 72 + q * 16];
                uint4 v1 = *(const uint4*)&Eb[d2 * 72 + q * 16 + 8];
                u16* dst = Ut + ((size_t)batch * 256 + n0 + d2) * LXV + VPAD + lrow0 + t * 64 + q * 16;
                *(uint4*)dst = v0;
                *(uint4*)(dst + 8) = v1;
            }
        }
        return;
    }

    // ================= Q / K path (R17-verified) =================
    const float* __restrict__ W = (mat == 0) ? Wq : Wk;
    const float* __restrict__ bias = (mat == 0) ? bq : bkb;

    {   // stage B once
        const int kp = tid & 31, ng = tid >> 5;
        u32* bd = (u32*)Bs;
        #pragma unroll
        for (int s = 0; s < 4; ++s) {
            const float* wr = W + (size_t)(s * 64 + 2 * kp) * 256 + n0 + ng * 8;
            float4 a0 = *(const float4*)(wr);
            float4 a1 = *(const float4*)(wr + 4);
            float4 b0 = *(const float4*)(wr + 256);
            float4 b1 = *(const float4*)(wr + 260);
            bd[(ng * 8 + 0) * 132 + s * 32 + kp] = pk2(a0.x, b0.x);
            bd[(ng * 8 + 1) * 132 + s * 32 + kp] = pk2(a0.y, b0.y);
            bd[(ng * 8 + 2) * 132 + s * 32 + kp] = pk2(a0.z, b0.z);
            bd[(ng * 8 + 3) * 132 + s * 32 + kp] = pk2(a0.w, b0.w);
            bd[(ng * 8 + 4) * 132 + s * 32 + kp] = pk2(a1.x, b1.x);
            bd[(ng * 8 + 5) * 132 + s * 32 + kp] = pk2(a1.y, b1.y);
            bd[(ng * 8 + 6) * 132 + s * 32 + kp] = pk2(a1.z, b1.z);
            bd[(ng * 8 + 7) * 132 + s * 32 + kp] = pk2(a1.w, b1.w);
        }
    }
    {   // stage A tile 0
        const int r = tid >> 2, cb = (tid & 3) * 64;
        const float* hp = H + (size_t)(row0 + r) * 256 + cb;
        const int swz = (r & 7) << 3;
        #pragma unroll
        for (int i = 0; i < 16; ++i) {
            float4 h4 = *(const float4*)(hp + i * 4);
            uint2 pv; pv.x = pk2(h4.x, h4.y); pv.y = pk2(h4.z, h4.w);
            *(uint2*)(As + ((r * 256 + cb + i * 4) ^ swz)) = pv;
        }
    }
    __syncthreads();

    for (int t = 0; t < 4; ++t) {
        f32x4 acc[2][2];
        #pragma unroll
        for (int rr = 0; rr < 2; ++rr)
            #pragma unroll
            for (int cc = 0; cc < 2; ++cc)
                acc[rr][cc] = (f32x4){0.f, 0.f, 0.f, 0.f};
        #pragma unroll
        for (int rr = 0; rr < 2; ++rr) {
            const int rowa = (rt2 + rr) * 16 + l15;
            const int swa = (rowa & 7) << 3;
            bf16x8 af[8];
            #pragma unroll
            for (int ks = 0; ks < 8; ++ks)
                af[ks] = *(const bf16x8*)(As + ((rowa * 256 + ks * 32 + lhi * 8) ^ swa));
            #pragma unroll
            for (int ks = 0; ks < 8; ++ks)
                #pragma unroll
                for (int cc = 0; cc < 2; ++cc) {
                    bf16x8 bf = *(const bf16x8*)&Bs[((ct2 + cc) * 16 + l15) * BSTR + ks * 32 + lhi * 8];
                    acc[rr][cc] = __builtin_amdgcn_mfma_f32_16x16x32_bf16(af[ks], bf, acc[rr][cc], 0, 0, 0);
                }
        }
        __syncthreads();

        #pragma unroll
        for (int cc = 0; cc < 2; ++cc) {
            const int cl = (ct2 + cc) * 16 + l15;
            const float bi = bias[n0 + cl];
            #pragma unroll
            for (int rr = 0; rr < 2; ++rr)
                #pragma unroll
                for (int reg = 0; reg < 4; ++reg)
                    Eb[((rt2 + rr) * 16 + lhi * 4 + reg) * 72 + cl] = f2bf(acc[rr][cc][reg] + bi);
        }
        if (t < 3) {
            const int r = tid >> 2, cb = (tid & 3) * 64;
            const float* hp = H + (size_t)(row0 + (t + 1) * 64 + r) * 256 + cb;
            const int swz = (r & 7) << 3;
            #pragma unroll
            for (int i = 0; i < 16; ++i) {
                float4 h4 = *(const float4*)(hp + i * 4);
                uint2 pv; pv.x = pk2(h4.x, h4.y); pv.y = pk2(h4.z, h4.w);
                *(uint2*)(As + ((r * 256 + cb + i * 4) ^ swz)) = pv;
            }
        }
        __syncthreads();

        {
            const int r2 = tid >> 2, c16 = (tid & 3) * 16;
            int rtile, rl;
            u16* base;
            if (mat == 0) {
                const int grow = row0 + t * 64 + r2;
                rtile = grow >> 4; rl = grow & 15;
                base = Qf;
            } else {
                const int prow = VPAD + lrow0 + t * 64 + r2;
                rtile = prow >> 4; rl = prow & 15;
                base = Kxf + (size_t)batch * KXFB;
            }
            #pragma unroll
            for (int h = 0; h < 2; ++h) {
                const int gcol = n0 + c16 + h * 8;
                const int ksq = gcol >> 5;
                const int lhq = (gcol >> 3) & 3;
                uint4 v = *(const uint4*)&Eb[r2 * 72 + c16 + h * 8];
                *(uint4*)&base[((size_t)rtile * 8 + ksq) * 512 + (rl * 4 + lhq) * 8] = v;
            }
        }
    }

    // Kxf virtual prefix (bk rows, fragment layout)
    if (bx == 4 && (by & 15) == 0) {
        const int batch2 = by >> 4;
        const int ks = tid >> 5, u = tid & 31;
        const u16 val = f2bf(bkb[ks * 32 + u]);
        u16* base = Kxf + (size_t)batch2 * KXFB;
        #pragma unroll
        for (int pt = 0; pt < 4; ++pt)
            #pragma unroll
            for (int rl = 0; rl < 16; ++rl)
                base[((size_t)pt * 8 + ks) * 512 + rl * 32 + u] = val;
    }
}

// ---------------- Kernel 2: attention + folded out-projection + residual ----------------
// R13-verified PU kernel + R17 XCD-chunked swizzle. 8.7 KB LDS, grid 512.
__global__ __launch_bounds__(256) void attn_out(
    const u16* __restrict__ Qf, const u16* __restrict__ Kxf,
    const u16* __restrict__ Ut, const float* __restrict__ bo,
    const float* __restrict__ H, float* __restrict__ out)
{
    __shared__ float Sb[QBLK * SSTR];
    __shared__ u16 Pb[QBLK * PSTR];

    const int tid = threadIdx.x;
    const int lane = tid & 63, w = tid >> 6;   // w 0..3
    const int l15 = lane & 15, lhi = lane >> 4;
    const int bid = blockIdx.x;
    const int r0 = (((bid & 7) << 6) + (bid >> 3)) * QBLK;   // XCD-chunked
    const int batch = r0 >> 12;
    const int lb0 = r0 & 4095;

    // ---- QK^T: 5 keytiles over 4 waves; fragments from global ----
    const float scale = 0.0625f;
    const int fidx = (l15 * 4 + lhi) * 8;
    const u16* qp = Qf + (size_t)(r0 >> 4) * 4096 + fidx;
    bf16x8 qf[8];
    #pragma unroll
    for (int ks = 0; ks < 8; ++ks) qf[ks] = *(const bf16x8*)(qp + ks * 512);

    const u16* kfb = Kxf + (size_t)batch * KXFB + (size_t)(lb0 >> 4) * 4096 + fidx;
    for (int T = w; T < 5; T += 4) {
        const u16* kp = kfb + (size_t)T * 4096;
        f32x4 acc = (f32x4){0.f, 0.f, 0.f, 0.f};
        #pragma unroll
        for (int ks = 0; ks < 8; ++ks) {
            bf16x8 kf = *(const bf16x8*)(kp + ks * 512);
            acc = __builtin_amdgcn_mfma_f32_16x16x32_bf16(qf[ks], kf, acc, 0, 0, 0);
        }
        #pragma unroll
        for (int reg = 0; reg < 4; ++reg)
            Sb[(lhi * 4 + reg) * SSTR + T * 16 + l15] = acc[reg] * scale;
    }
    __syncthreads();

    // ---- nested softmax ----
    {
        const int ri = w * 4 + lhi;
        const int jb = l15;
        float s5[5];
        float m = -1e30f;
        #pragma unroll
        for (int c = 0; c < 5; ++c) {
            const int j = jb + 16 * c;
            const float x = Sb[ri * SSTR + j];
            const bool v = (j >= ri + 1) && (j <= ri + 64);
            s5[c] = v ? x : -1e30f;
            m = fmaxf(m, s5[c]);
        }
        #pragma unroll
        for (int o = 1; o < 16; o <<= 1) m = fmaxf(m, __shfl_xor(m, o));
        float e5[5], z64 = 0.f, z16 = 0.f, z4 = 0.f;
        #pragma unroll
        for (int c = 0; c < 5; ++c) {
            const int j = jb + 16 * c;
            const float e = __expf(s5[c] - m);
            e5[c] = e;
            z64 += e;
            if (j >= ri + 49) z16 += e;
            if (j >= ri + 61) z4 += e;
        }
        #pragma unroll
        for (int o = 1; o < 16; o <<= 1) {
            z64 += __shfl_xor(z64, o);
            z16 += __shfl_xor(z16, o);
            z4  += __shfl_xor(z4, o);
        }
        const float i64 = 1.f / z64, i16 = 1.f / z16, i4 = 1.f / z4;
        #pragma unroll
        for (int c = 0; c < 5; ++c) {
            const int j = jb + 16 * c;
            float wt = e5[c] * (i64 + (j >= ri + 49 ? i16 : 0.f) + (j >= ri + 61 ? i4 : 0.f)) * (1.f / 3.f);
            Pb[ri * PSTR + j] = f2bf(wt);
        }
        Pb[ri * PSTR + 80 + jb] = 0;
    }
    __syncthreads();

    // ---- P @ U^T: out[16][256] = H + P[16][96] @ U^T[96][256] + bo ----
    bf16x8 pa[3];
    #pragma unroll
    for (int ks = 0; ks < 3; ++ks)
        pa[ks] = *(const bf16x8*)&Pb[l15 * PSTR + ks * 32 + lhi * 8];
    #pragma unroll
    for (int i = 0; i < 4; ++i) {
        const int dt = w * 4 + i;
        const u16* urow = Ut + ((size_t)batch * 256 + dt * 16 + l15) * LXV + lb0;
        f32x4 acc = (f32x4){0.f, 0.f, 0.f, 0.f};
        #pragma unroll
        for (int ks = 0; ks < 3; ++ks) {
            bf16x8 ub = *(const bf16x8*)(urow + ks * 32 + lhi * 8);
            acc = __builtin_amdgcn_mfma_f32_16x16x32_bf16(pa[ks], ub, acc, 0, 0, 0);
        }
        const int col = dt * 16 + l15;
        const float bi = bo[col];
        #pragma unroll
        for (int reg = 0; reg < 4; ++reg) {
            const int r = r0 + lhi * 4 + reg;
            const size_t off = (size_t)r * 256 + col;
            out[off] = H[off] + acc[reg] + bi;
        }
    }
}

extern "C" void kernel_launch(void* const* d_in, const int* in_sizes, int n_in,
                              void* d_out, int out_size, void* d_ws, size_t ws_size,
                              hipStream_t stream) {
    const float* H  = (const float*)d_in[0];
    const float* Wq = (const float*)d_in[1];
    const float* bq = (const float*)d_in[2];
    const float* Wk = (const float*)d_in[3];
    const float* bk = (const float*)d_in[4];
    const float* Wv = (const float*)d_in[5];
    const float* bv = (const float*)d_in[6];
    const float* Wo = (const float*)d_in[7];
    const float* bo = (const float*)d_in[8];
    float* out = (float*)d_out;

    u16* Qf   = (u16*)d_ws;                        // 8192*256 (fragment layout)
    u16* Kxf  = Qf + (size_t)NROWS * 256;          // 2*KXFB (fragment layout)
    u16* Ut   = Kxf + (size_t)2 * KXFB;            // 2*256*LXV (transposed U)
    u16* WvoS = Ut + (size_t)2 * 256 * LXV;        // 4 slabs * 64*256 bf16 (packed)

    qkv_mfma<<<dim3(32, 12), 256, 0, stream>>>(H, Wq, Wk, Wv, Wo, bq, bk, bv, Qf, Kxf, Ut, WvoS);
    attn_out<<<512, 256, 0, stream>>>(Qf, Kxf, Ut, bo, H, out);
}

// Round 21
// 43.587 us; speedup vs baseline: 1.4715x; 1.4715x over previous
//
#include <hip/hip_runtime.h>
#include <hip/hip_bf16.h>

#define D 256
#define NROWS 8192
#define LXV 4176         // Vt col stride per batch: 64 prefix + 4096 + 16 tail pad
#define VPAD 64
#define KXFB 1064960     // Kxf batch stride (u16): 260 tiles * 8 ks * 512

#define QBLK 16          // attn rows per block
#define SSTR 84          // Sb row stride (f32)
#define PSTR 104         // Pb row stride (u16), cols 80..95 zeroed
#define MSTR 264         // Ml row stride (u16)
#define BSTR 264         // Bs row stride (u16)

typedef unsigned int u32;
typedef unsigned short u16;

typedef short bf16x8 __attribute__((ext_vector_type(8)));
typedef float f32x4 __attribute__((ext_vector_type(4)));

__device__ __forceinline__ u16 f2bf(float f) {
    u32 x = __float_as_uint(f);
    x += 0x7fffu + ((x >> 16) & 1u);
    return (u16)(x >> 16);
}
__device__ __forceinline__ u32 pk2(float a, float b) {
    return (u32)f2bf(a) | ((u32)f2bf(b) << 16);
}

// ---------------- Kernel 1: QKV projection (Q/K/Wo in fragment layout) ----------------
// grid (32, 12): blockIdx.x = row-group (FAST dim), blockIdx.y = 64-col slab.
// XCD locality: the 12 blocks sharing a row-group have bids 32 apart == same (mod 8)
// -> same XCD -> H tile L2-shared instead of 12x HBM.
__global__ __launch_bounds__(256) void qkv_mfma(
    const float* __restrict__ H,
    const float* __restrict__ Wq, const float* __restrict__ Wk,
    const float* __restrict__ Wv, const float* __restrict__ Wo,
    const float* __restrict__ bq, const float* __restrict__ bkb,
    const float* __restrict__ bvb,
    u16* __restrict__ Qf, u16* __restrict__ Kxf, u16* __restrict__ Vt,
    u16* __restrict__ WoTf)
{
    __shared__ u16 As[64 * 256];        // 32768 B
    __shared__ u16 Bs[64 * BSTR];       // 33792 B
    __shared__ u16 Eb[64 * 72];         // 9216 B

    const int tid = threadIdx.x;
    const int by = blockIdx.x;          // 0..31  (row group)   [FAST -> XCD-shared H]
    const int bx = blockIdx.y;          // 0..11  (col slab)
    const int mat = bx >> 2;            // 0=Q 1=K 2=V
    const int n0 = (bx & 3) * 64;
    const int row0 = by * 256;
    const int batch = by >> 4;
    const int lrow0 = row0 & 4095;
    const float* __restrict__ W = (mat == 0) ? Wq : (mat == 1) ? Wk : Wv;
    const float* __restrict__ bias = (mat == 0) ? bq : (mat == 1) ? bkb : bvb;

    const int lane = tid & 63, w = tid >> 6;
    const int l15 = lane & 15, lhi = lane >> 4;
    const int rt2 = (w & 1) * 2, ct2 = (w >> 1) * 2;

    // ---- stage B once ----
    {
        const int kp = tid & 31, ng = tid >> 5;
        u32* bd = (u32*)Bs;
        #pragma unroll
        for (int s = 0; s < 4; ++s) {
            const float* wr = W + (size_t)(s * 64 + 2 * kp) * 256 + n0 + ng * 8;
            float4 a0 = *(const float4*)(wr);
            float4 a1 = *(const float4*)(wr + 4);
            float4 b0 = *(const float4*)(wr + 256);
            float4 b1 = *(const float4*)(wr + 260);
            bd[(ng * 8 + 0) * 132 + s * 32 + kp] = pk2(a0.x, b0.x);
            bd[(ng * 8 + 1) * 132 + s * 32 + kp] = pk2(a0.y, b0.y);
            bd[(ng * 8 + 2) * 132 + s * 32 + kp] = pk2(a0.z, b0.z);
            bd[(ng * 8 + 3) * 132 + s * 32 + kp] = pk2(a0.w, b0.w);
            bd[(ng * 8 + 4) * 132 + s * 32 + kp] = pk2(a1.x, b1.x);
            bd[(ng * 8 + 5) * 132 + s * 32 + kp] = pk2(a1.y, b1.y);
            bd[(ng * 8 + 6) * 132 + s * 32 + kp] = pk2(a1.z, b1.z);
            bd[(ng * 8 + 7) * 132 + s * 32 + kp] = pk2(a1.w, b1.w);
        }
    }
    // ---- stage A tile 0 ----
    {
        const int r = tid >> 2, cb = (tid & 3) * 64;
        const float* hp = H + (size_t)(row0 + r) * 256 + cb;
        const int swz = (r & 7) << 3;
        #pragma unroll
        for (int i = 0; i < 16; ++i) {
            float4 h4 = *(const float4*)(hp + i * 4);
            uint2 pv; pv.x = pk2(h4.x, h4.y); pv.y = pk2(h4.z, h4.w);
            *(uint2*)(As + ((r * 256 + cb + i * 4) ^ swz)) = pv;
        }
    }
    __syncthreads();

    for (int t = 0; t < 4; ++t) {
        f32x4 acc[2][2];
        #pragma unroll
        for (int rr = 0; rr < 2; ++rr)
            #pragma unroll
            for (int cc = 0; cc < 2; ++cc)
                acc[rr][cc] = (f32x4){0.f, 0.f, 0.f, 0.f};
        #pragma unroll
        for (int rr = 0; rr < 2; ++rr) {
            const int rowa = (rt2 + rr) * 16 + l15;
            const int swa = (rowa & 7) << 3;
            bf16x8 af[8];
            #pragma unroll
            for (int ks = 0; ks < 8; ++ks)
                af[ks] = *(const bf16x8*)(As + ((rowa * 256 + ks * 32 + lhi * 8) ^ swa));
            #pragma unroll
            for (int ks = 0; ks < 8; ++ks)
                #pragma unroll
                for (int cc = 0; cc < 2; ++cc) {
                    bf16x8 bf = *(const bf16x8*)&Bs[((ct2 + cc) * 16 + l15) * BSTR + ks * 32 + lhi * 8];
                    acc[rr][cc] = __builtin_amdgcn_mfma_f32_16x16x32_bf16(af[ks], bf, acc[rr][cc], 0, 0, 0);
                }
        }
        __syncthreads();

        // ---- epilogue writes (Eb) + next A stage ----
        if (mat == 2) {
            #pragma unroll
            for (int cc = 0; cc < 2; ++cc) {
                const int dl = (ct2 + cc) * 16 + l15;
                const float bi = bvb[n0 + dl];
                #pragma unroll
                for (int rr = 0; rr < 2; ++rr)
                    #pragma unroll
                    for (int reg = 0; reg < 4; ++reg)
                        Eb[dl * 72 + (rt2 + rr) * 16 + lhi * 4 + reg] = f2bf(acc[rr][cc][reg] + bi);
            }
        } else {
            #pragma unroll
            for (int cc = 0; cc < 2; ++cc) {
                const int cl = (ct2 + cc) * 16 + l15;
                const float bi = bias[n0 + cl];
                #pragma unroll
                for (int rr = 0; rr < 2; ++rr)
                    #pragma unroll
                    for (int reg = 0; reg < 4; ++reg)
                        Eb[((rt2 + rr) * 16 + lhi * 4 + reg) * 72 + cl] = f2bf(acc[rr][cc][reg] + bi);
            }
        }
        if (t < 3) {
            const int r = tid >> 2, cb = (tid & 3) * 64;
            const float* hp = H + (size_t)(row0 + (t + 1) * 64 + r) * 256 + cb;
            const int swz = (r & 7) << 3;
            #pragma unroll
            for (int i = 0; i < 16; ++i) {
                float4 h4 = *(const float4*)(hp + i * 4);
                uint2 pv; pv.x = pk2(h4.x, h4.y); pv.y = pk2(h4.z, h4.w);
                *(uint2*)(As + ((r * 256 + cb + i * 4) ^ swz)) = pv;
            }
        }
        __syncthreads();

        // ---- coalesced stores from Eb ----
        if (mat == 2) {
            const int d2 = tid >> 2, q = tid & 3;
            uint4 v0 = *(const uint4*)&Eb[d2 * 72 + q * 16];
            uint4 v1 = *(const uint4*)&Eb[d2 * 72 + q * 16 + 8];
            u16* dst = Vt + ((size_t)batch * 256 + n0 + d2) * LXV + VPAD + lrow0 + t * 64 + q * 16;
            *(uint4*)dst = v0;
            *(uint4*)(dst + 8) = v1;
        } else {
            const int r2 = tid >> 2, c16 = (tid & 3) * 16;
            int rtile, rl;
            u16* base;
            if (mat == 0) {
                const int grow = row0 + t * 64 + r2;
                rtile = grow >> 4; rl = grow & 15;
                base = Qf;
            } else {
                const int prow = VPAD + lrow0 + t * 64 + r2;
                rtile = prow >> 4; rl = prow & 15;
                base = Kxf + (size_t)batch * KXFB;
            }
            #pragma unroll
            for (int h = 0; h < 2; ++h) {
                const int gcol = n0 + c16 + h * 8;
                const int ksq = gcol >> 5;
                const int lhq = (gcol >> 3) & 3;
                uint4 v = *(const uint4*)&Eb[r2 * 72 + c16 + h * 8];
                *(uint4*)&base[((size_t)rtile * 8 + ksq) * 512 + (rl * 4 + lhq) * 8] = v;
            }
        }
    }

    // ---- WoTf production: 16 blocks, one 64x64 tile each, fragment layout ----
    if (bx == 0 && by < 16) {
        float* Tf = (float*)As;     // [64][68] f32
        const int tr = by >> 2, tc = by & 3;
        __syncthreads();
        {
            const int r = tid >> 2, c0 = (tid & 3) * 16;
            const float* src = Wo + (size_t)(tr * 64 + r) * 256 + tc * 64 + c0;
            #pragma unroll
            for (int i = 0; i < 4; ++i) {
                float4 v = *(const float4*)(src + i * 4);
                Tf[r * 68 + c0 + i * 4 + 0] = v.x;
                Tf[r * 68 + c0 + i * 4 + 1] = v.y;
                Tf[r * 68 + c0 + i * 4 + 2] = v.z;
                Tf[r * 68 + c0 + i * 4 + 3] = v.w;
            }
        }
        __syncthreads();
        {
            const int n = tid >> 2, k0 = (tid & 3) * 16;
            const int gcol = tc * 64 + n;
            const int colt = gcol >> 4, cl = gcol & 15;
            const int gk = tr * 64 + k0;
            const int ksw = gk >> 5;
            const int lhw = (gk >> 3) & 3;
            u32 pw[8];
            #pragma unroll
            for (int i = 0; i < 8; ++i)
                pw[i] = pk2(Tf[(k0 + 2 * i) * 68 + n], Tf[(k0 + 2 * i + 1) * 68 + n]);
            u16* base = WoTf + ((size_t)colt * 8 + ksw) * 512 + (cl * 4 + lhw) * 8;
            *(uint4*)base = *(uint4*)&pw[0];
            *(uint4*)(base + 8) = *(uint4*)&pw[4];
        }
    }
    // ---- virtual prefixes ----
    if (bx == 4 && (by & 15) == 0) {          // Kxf prefix ptiles 0..3 = bk (fragment layout)
        const int batch2 = by >> 4;
        const int ks = tid >> 5, u = tid & 31;
        const u16 val = f2bf(bkb[ks * 32 + u]);
        u16* base = Kxf + (size_t)batch2 * KXFB;
        #pragma unroll
        for (int pt = 0; pt < 4; ++pt)
            #pragma unroll
            for (int rl = 0; rl < 16; ++rl)
                base[((size_t)pt * 8 + ks) * 512 + rl * 32 + u] = val;
    }
    if (bx == 8 && (by & 15) == 0) {          // Vt prefix cols = bv
        const int batch2 = by >> 4;
        const u16 val = f2bf(bvb[tid]);
        const u32 vv = (u32)val | ((u32)val << 16);
        uint4 o; o.x = vv; o.y = vv; o.z = vv; o.w = vv;
        u16* dst = Vt + ((size_t)batch2 * 256 + tid) * LXV;
        #pragma unroll
        for (int j = 0; j < 8; ++j) *(uint4*)(dst + j * 8) = o;
    }
}

// ---------------- Kernel 2: fused attention + out-projection + residual ----------------
// 16 rows/block, grid 512, 17.2 KB LDS. XCD-chunked swizzle: bid -> r0idx =
// (bid%8)*64 + bid/8 (bijective), so each XCD serves 64 consecutive row-blocks
// whose overlapping sliding-window K/V tiles stay L2-resident.
__global__ __launch_bounds__(256) void attn_out(
    const u16* __restrict__ Qf, const u16* __restrict__ Kxf,
    const u16* __restrict__ Vt, const u16* __restrict__ WoTf,
    const float* __restrict__ bo, const float* __restrict__ H,
    float* __restrict__ out)
{
    __shared__ float Sb[QBLK * SSTR];
    __shared__ u16 Pb[QBLK * PSTR];
    __shared__ u16 Ml[QBLK * MSTR];

    const int tid = threadIdx.x;
    const int lane = tid & 63, w = tid >> 6;   // w 0..3
    const int l15 = lane & 15, lhi = lane >> 4;
    const int bid = blockIdx.x;
    const int r0 = (((bid & 7) << 6) + (bid >> 3)) * QBLK;   // XCD-chunked
    const int batch = r0 >> 12;
    const int lb0 = r0 & 4095;

    // ---- QK^T: 5 keytiles over 4 waves; all fragments from global ----
    const float scale = 0.0625f;
    const int fidx = (l15 * 4 + lhi) * 8;
    const u16* qp = Qf + (size_t)(r0 >> 4) * 4096 + fidx;
    bf16x8 qf[8];
    #pragma unroll
    for (int ks = 0; ks < 8; ++ks) qf[ks] = *(const bf16x8*)(qp + ks * 512);

    const u16* kfb = Kxf + (size_t)batch * KXFB + (size_t)(lb0 >> 4) * 4096 + fidx;
    for (int T = w; T < 5; T += 4) {
        const u16* kp = kfb + (size_t)T * 4096;
        f32x4 acc = (f32x4){0.f, 0.f, 0.f, 0.f};
        #pragma unroll
        for (int ks = 0; ks < 8; ++ks) {
            bf16x8 kf = *(const bf16x8*)(kp + ks * 512);
            acc = __builtin_amdgcn_mfma_f32_16x16x32_bf16(qf[ks], kf, acc, 0, 0, 0);
        }
        #pragma unroll
        for (int reg = 0; reg < 4; ++reg)
            Sb[(lhi * 4 + reg) * SSTR + T * 16 + l15] = acc[reg] * scale;
    }
    __syncthreads();

    // ---- nested softmax ----
    {
        const int ri = w * 4 + lhi;
        const int jb = l15;
        float s5[5];
        float m = -1e30f;
        #pragma unroll
        for (int c = 0; c < 5; ++c) {
            const int j = jb + 16 * c;
            const float x = Sb[ri * SSTR + j];
            const bool v = (j >= ri + 1) && (j <= ri + 64);
            s5[c] = v ? x : -1e30f;
            m = fmaxf(m, s5[c]);
        }
        #pragma unroll
        for (int o = 1; o < 16; o <<= 1) m = fmaxf(m, __shfl_xor(m, o));
        float e5[5], z64 = 0.f, z16 = 0.f, z4 = 0.f;
        #pragma unroll
        for (int c = 0; c < 5; ++c) {
            const int j = jb + 16 * c;
            const float e = __expf(s5[c] - m);
            e5[c] = e;
            z64 += e;
            if (j >= ri + 49) z16 += e;
            if (j >= ri + 61) z4 += e;
        }
        #pragma unroll
        for (int o = 1; o < 16; o <<= 1) {
            z64 += __shfl_xor(z64, o);
            z16 += __shfl_xor(z16, o);
            z4  += __shfl_xor(z4, o);
        }
        const float i64 = 1.f / z64, i16 = 1.f / z16, i4 = 1.f / z4;
        #pragma unroll
        for (int c = 0; c < 5; ++c) {
            const int j = jb + 16 * c;
            float wt = e5[c] * (i64 + (j >= ri + 49 ? i16 : 0.f) + (j >= ri + 61 ? i4 : 0.f)) * (1.f / 3.f);
            Pb[ri * PSTR + j] = f2bf(wt);
        }
        Pb[ri * PSTR + 80 + jb] = 0;
    }
    __syncthreads();

    // ---- PV: M[16][256] -> Ml (LDS); V fragments from global ----
    bf16x8 pa[3];
    #pragma unroll
    for (int ks = 0; ks < 3; ++ks)
        pa[ks] = *(const bf16x8*)&Pb[l15 * PSTR + ks * 32 + lhi * 8];
    #pragma unroll
    for (int i = 0; i < 4; ++i) {
        const int dt = w * 4 + i;
        const u16* vrow = Vt + ((size_t)batch * 256 + dt * 16 + l15) * LXV + lb0;
        f32x4 acc = (f32x4){0.f, 0.f, 0.f, 0.f};
        #pragma unroll
        for (int ks = 0; ks < 3; ++ks) {
            bf16x8 vb = *(const bf16x8*)(vrow + ks * 32 + lhi * 8);
            acc = __builtin_amdgcn_mfma_f32_16x16x32_bf16(pa[ks], vb, acc, 0, 0, 0);
        }
        #pragma unroll
        for (int reg = 0; reg < 4; ++reg)
            Ml[(lhi * 4 + reg) * MSTR + dt * 16 + l15] = f2bf(acc[reg]);
    }
    __syncthreads();

    // ---- out-GEMM: Wo fragments coalesced from WoTf ----
    bf16x8 afm[8];
    #pragma unroll
    for (int ks = 0; ks < 8; ++ks)
        afm[ks] = *(const bf16x8*)&Ml[l15 * MSTR + ks * 32 + lhi * 8];

    #pragma unroll
    for (int ct = 0; ct < 4; ++ct) {
        const int colt = w * 4 + ct;
        const u16* wrow = WoTf + (size_t)colt * 4096 + fidx;
        f32x4 oac = (f32x4){0.f, 0.f, 0.f, 0.f};
        #pragma unroll
        for (int ks = 0; ks < 8; ++ks) {
            bf16x8 bf = *(const bf16x8*)(wrow + ks * 512);
            oac = __builtin_amdgcn_mfma_f32_16x16x32_bf16(afm[ks], bf, oac, 0, 0, 0);
        }
        const int col = w * 64 + ct * 16 + l15;
        const float bi = bo[col];
        #pragma unroll
        for (int reg = 0; reg < 4; ++reg) {
            const int r = r0 + lhi * 4 + reg;
            const size_t off = (size_t)r * 256 + col;
            out[off] = H[off] + oac[reg] + bi;
        }
    }
}

extern "C" void kernel_launch(void* const* d_in, const int* in_sizes, int n_in,
                              void* d_out, int out_size, void* d_ws, size_t ws_size,
                              hipStream_t stream) {
    const float* H  = (const float*)d_in[0];
    const float* Wq = (const float*)d_in[1];
    const float* bq = (const float*)d_in[2];
    const float* Wk = (const float*)d_in[3];
    const float* bk = (const float*)d_in[4];
    const float* Wv = (const float*)d_in[5];
    const float* bv = (const float*)d_in[6];
    const float* Wo = (const float*)d_in[7];
    const float* bo = (const float*)d_in[8];
    float* out = (float*)d_out;

    u16* Qf   = (u16*)d_ws;                        // 8192*256 (fragment layout)
    u16* Kxf  = Qf + (size_t)NROWS * 256;          // 2*KXFB (fragment layout)
    u16* Vt   = Kxf + (size_t)2 * KXFB;            // 2*256*LXV
    u16* WoTf = Vt + (size_t)2 * 256 * LXV;        // 256*256 (fragment layout)

    qkv_mfma<<<dim3(32, 12), 256, 0, stream>>>(H, Wq, Wk, Wv, Wo, bq, bk, bv, Qf, Kxf, Vt, WoTf);
    attn_out<<<512, 256, 0, stream>>>(Qf, Kxf, Vt, WoTf, bo, H, out);
}